// Round 12
// baseline (290.620 us; speedup 1.0000x reference)
//
#include <hip/hip_runtime.h>
#include <hip/hip_bf16.h>

// Problem: B=8, T_OUT=256, T_IN=512, L=128, D_IN=128, D_ATT=128 (f32 in/out).
// R19 = R18 resubmit (Round-11 bench died with "MI355X container failed
// twice" -- broker/provisioning error, same signature as Round 4 whose
// unchanged resubmit then PASSED; full deadlock/resource re-audit found no
// defect). Experiment: make the PUB wait provably zero.
//   - cadence 8, PUB = vmcnt(24): 32 vmem ops (16 xf stores + 16 pf loads)
//     are newer than xf(t-16); waiting to <=24 outstanding proves xf(t-16)
//     drained while never touching anything < ~8 steps old. PUBs halve.
//     Publish prog = t-15 (claims rows <= t-16; worker reads rows <= prog-1).
//   - prefetch issued BEFORE the barrier (R7 position; can't stall now).
// Scan core / workers / prologue / 1-blk-per-CU LDS pad: R17-exact.
// Read-out: fused ~193-198 -> residual PUB stalls were real. Flat ~202 ->
// all named mechanisms exonerated; serial-chain floor; declare ROOFLINE.
//
// ws layout (float elements):
#define XF_OFF   0         // f32 x[8*256*128]
#define PROG_OFF 524288    // int prog0 @ +0, prog1 @ +64 (256B apart)
#define XZ_OFF   1048576   // f16[8*256*512] region (2 MB)
#define KEYS_OFF 2097152   // f32 keysT[8][128][512], PRESCALED by CSCALE
// out layout (f32): out(8,256,256) @0, h(8,128) @524288, c(8,128) @525312
#define OUT_H    524288
#define OUT_C    525312

#define LDS_BARRIER() __asm__ __volatile__("s_waitcnt lgkmcnt(0)\n\ts_barrier" ::: "memory")
// Publication barrier: proves xf(t-16) and older drained (32 newer ops in
// flight, wait to <=24) without waiting on anything recent -> 0 cost.
#define PUB_BARRIER() __asm__ __volatile__("s_waitcnt vmcnt(24) lgkmcnt(0)\n\ts_barrier" ::: "memory")

#if __has_builtin(__builtin_amdgcn_exp2f)
#define EXP2F __builtin_amdgcn_exp2f
#else
#define EXP2F exp2f
#endif

typedef _Float16 f16x8 __attribute__((ext_vector_type(8)));
typedef float fx4 __attribute__((ext_vector_type(4)));

__device__ __forceinline__ float fast_rcp(float x) { return __builtin_amdgcn_rcpf(x); }
__device__ __forceinline__ float fast_sig(float v) { return fast_rcp(1.f + __expf(-v)); }
__device__ __forceinline__ float fast_tanh(float v) { return 2.f * fast_rcp(1.f + __expf(-2.f * v)) - 1.f; }

// C = -2*log2(e): tanh(v) = 2*rcp(1+exp2(C*v)) - 1
#define CSCALE (-2.8853900817779268f)

// ---------------- Kernel 1: xz prologue (blocks 0-255) + keysT GEMM (256-511) ----------------
__global__ __launch_bounds__(256)
void prologue_k(const float* __restrict__ inp, const float* __restrict__ Wk,
                const float* __restrict__ bias, const float* __restrict__ att,
                const float* __restrict__ W1, const float* __restrict__ b1,
                float* __restrict__ ws) {
  __shared__ float ar[8][128];
  __shared__ float ar2[16][128];
  const int tid = threadIdx.x;

  if (blockIdx.x < 256) {
    // ---- xz = inputs @ Wk + bias, f16 [t][b][u][gate] ----
    _Float16* xz16 = (_Float16*)(ws + XZ_OFF);
    const int row0 = blockIdx.x * 8;
    for (int i = tid; i < 8 * 128; i += 256) ar[i >> 7][i & 127] = inp[row0 * 128 + i];
    __syncthreads();
    float acc[8][2];
    const float bb0 = bias[tid], bb1 = bias[tid + 256];
#pragma unroll
    for (int r = 0; r < 8; ++r) { acc[r][0] = bb0; acc[r][1] = bb1; }
    for (int d = 0; d < 128; d += 4) {
      float w0a = Wk[(d + 0) * 512 + tid], w0b = Wk[(d + 0) * 512 + tid + 256];
      float w1a = Wk[(d + 1) * 512 + tid], w1b = Wk[(d + 1) * 512 + tid + 256];
      float w2a = Wk[(d + 2) * 512 + tid], w2b = Wk[(d + 2) * 512 + tid + 256];
      float w3a = Wk[(d + 3) * 512 + tid], w3b = Wk[(d + 3) * 512 + tid + 256];
#pragma unroll
      for (int r = 0; r < 8; ++r) {
        float4 a4 = *(const float4*)&ar[r][d];
        acc[r][0] += a4.x * w0a + a4.y * w1a + a4.z * w2a + a4.w * w3a;
        acc[r][1] += a4.x * w0b + a4.y * w1b + a4.z * w2b + a4.w * w3b;
      }
    }
    const int u = tid & 127, g0 = tid >> 7;
#pragma unroll
    for (int r = 0; r < 8; ++r) {
      const int row = row0 + r, b = row >> 8, t = row & 255;
      const int base = ((t * 8 + b) * 128 + u) * 4;
      xz16[base + g0]     = (_Float16)acc[r][0];
      xz16[base + g0 + 2] = (_Float16)acc[r][1];
    }
    return;
  }

  // ---- keysT[b][l][k] = CSCALE * ((attended @ W1 + b1))^T : 16 k-rows per block ----
  if (blockIdx.x == 256 && tid < 2) ((int*)(ws + PROG_OFF))[tid * 64] = 0;  // padded prog cells
  const int kb = blockIdx.x - 256;
  const int row0 = kb * 16;              // global row in (b*512 + k)
  const int bq = row0 >> 9, k0 = row0 & 511;
  for (int i = tid; i < 16 * 128; i += 256) ar2[i >> 7][i & 127] = att[row0 * 128 + i];
  __syncthreads();
  const int l = tid & 127, r0 = tid >> 7;  // r0 in 0..1
  float acc[8];
  const float bl = b1[l];
#pragma unroll
  for (int i = 0; i < 8; ++i) acc[i] = bl;
  for (int d = 0; d < 128; d += 4) {
    float w0 = W1[(d + 0) * 128 + l], w1 = W1[(d + 1) * 128 + l];
    float w2 = W1[(d + 2) * 128 + l], w3 = W1[(d + 3) * 128 + l];
#pragma unroll
    for (int i = 0; i < 8; ++i) {
      float4 a4 = *(const float4*)&ar2[r0 * 8 + i][d];
      acc[i] += a4.x * w0 + a4.y * w1 + a4.z * w2 + a4.w * w3;
    }
  }
  float* kT = ws + KEYS_OFF + (bq * 128 + l) * 512 + k0 + r0 * 8;
  float4 lo = {CSCALE * acc[0], CSCALE * acc[1], CSCALE * acc[2], CSCALE * acc[3]};
  float4 hi = {CSCALE * acc[4], CSCALE * acc[5], CSCALE * acc[6], CSCALE * acc[7]};
  *(float4*)kT = lo;
  *(float4*)(kT + 4) = hi;
}

// ---------------- Kernel 2: fused LSTM scan (blocks 0-1) + attention workers ----------------
struct ScanS { _Float16 hb[2][576]; };                       // 2.25 KB (overlay)
struct AttnS {                                               // 45568 B
  float kc[2][8][512];    // keysT strip double-buffer (prescaled)
  float xr[4][128];       // staged x rows
  float qp[4][128];       // q projection (prescaled by CSCALE)
  float sc[4][512];       // scores -> probs
  float w3s[128];         // 2*W3
};

__global__ __launch_bounds__(512)
void fused_scan_attn(const float* __restrict__ Wrf, const float* __restrict__ att,
                     const float* __restrict__ W2c, const float* __restrict__ b2c,
                     const float* __restrict__ W3c, const float* __restrict__ b3c,
                     float* __restrict__ ws, float* __restrict__ out) {
  // 86016B static LDS -> 1 block/CU kernel-wide (R17, verified neutral-safe).
  __shared__ __align__(16) char smem[86016];
  const int tid = threadIdx.x;
  int* prog = (int*)(ws + PROG_OFF);   // cells at [0] and [64] (256B apart)
  float* xf = ws + XF_OFF;

  if (blockIdx.x >= 2) {
    // ================= attention worker: chunks {w, 511-w}, earlier q0 first =================
    AttnS* A = (AttnS*)smem;
    const int wkr = (int)blockIdx.x - 2;  // 0..255
    int cA = wkr, cB = 511 - wkr;
    if ((cA & 63) > (cB & 63)) { int tmp = cA; cA = cB; cB = tmp; }
    if (tid < 128) A->w3s[tid] = 2.f * W3c[tid];
    // sum(w3) for the tanh->rcp correction (once; W3 is L2-hot)
    float sw3 = 0.f;
    for (int ll = 0; ll < 128; ll += 4) {
      float4 w4 = *(const float4*)&W3c[ll];
      sw3 += w4.x + w4.y + w4.z + w4.w;
    }
    const int l = tid & 127, r0 = tid >> 7;    // one thread per (row, l); r0 in 0..3
    for (int ci = 0; ci < 2; ++ci) {
      const int c = ci ? cB : cA;
      const int b = c >> 6, q0 = (c & 63) * 4;
      if (tid == 0) {
        int pv;
        while ((pv = __hip_atomic_load(&prog[(b >> 2) * 64], __ATOMIC_RELAXED,
                                       __HIP_MEMORY_SCOPE_AGENT)) < q0 + 4) {
          if (q0 + 4 - pv > 32) __builtin_amdgcn_s_sleep(127);   // far: 3.4us backoff
          else                  __builtin_amdgcn_s_sleep(8);     // near: 0.34us
        }
      }
      __syncthreads();   // wake barrier; also orders w3s (ci=0) / prev chunk's sc reads (ci=1)
      const int row = b * 256 + q0 + r0;
      const float xv = __hip_atomic_load(&xf[row * 128 + l], __ATOMIC_RELAXED, __HIP_MEMORY_SCOPE_AGENT);
      A->xr[r0][l] = xv;
      out[row * 256 + l] = xv;
      __syncthreads();
      // ---- qproj (prescaled): qp[r0][l] = CSCALE*(x@W2 + b2) ----
      float qa = b2c[l];
      for (int d = 0; d < 128; d += 4) {
        float4 x4 = *(const float4*)&A->xr[r0][d];
        qa += x4.x * W2c[(d + 0) * 128 + l] + x4.y * W2c[(d + 1) * 128 + l]
            + x4.z * W2c[(d + 2) * 128 + l] + x4.w * W2c[(d + 3) * 128 + l];
      }
      A->qp[r0][l] = CSCALE * qa;      // published by first strip barrier below
      const float base = b3c[0] - sw3;   // b3 + sum_l(-w3): tanh = 2r-1 correction
      // ---- scores: dbuf kc staging, issue-early/write-late, 1 barrier/strip ----
      float acc0 = base, acc1 = base, acc2 = base, acc3 = base;
      const float* keysT = ws + KEYS_OFF + b * (128 * 512);   // prescaled
      float rg[8];
#pragma unroll
      for (int k = 0; k < 8; ++k) rg[k] = keysT[tid + 512 * k];   // strip 0 -> regs
      {
        float* kw = &A->kc[0][0][0];
#pragma unroll
        for (int k = 0; k < 8; ++k) kw[tid + 512 * k] = rg[k];    // strip 0 -> buf 0
      }
      int cur = 0;
      for (int cc = 0; cc < 128; cc += 8) {
        const bool has_next = (cc + 8) < 128;
        if (has_next) {
          const float* nb = keysT + (cc + 8) * 512;
#pragma unroll
          for (int k = 0; k < 8; ++k) rg[k] = nb[tid + 512 * k];  // issue early
        }
        __syncthreads();   // buf[cur] writes (+qp on first strip) visible
        const float* kb = &A->kc[cur][0][0];
#pragma unroll
        for (int lp = 0; lp < 8; ++lp) {
          const float qv = A->qp[r0][cc + lp];  // LDS broadcast
          const float wv = A->w3s[cc + lp];     // LDS broadcast, = 2*w3
          const float* kr = kb + lp * 512;
          acc0 += fast_rcp(1.f + EXP2F(kr[l]       + qv)) * wv;
          acc1 += fast_rcp(1.f + EXP2F(kr[l + 128] + qv)) * wv;
          acc2 += fast_rcp(1.f + EXP2F(kr[l + 256] + qv)) * wv;
          acc3 += fast_rcp(1.f + EXP2F(kr[l + 384] + qv)) * wv;
        }
        if (has_next) {
          float* kw = &A->kc[cur ^ 1][0][0];
#pragma unroll
          for (int k = 0; k < 8; ++k) kw[tid + 512 * k] = rg[k];  // write late
        }
        cur ^= 1;
      }
      A->sc[r0][l]       = acc0;
      A->sc[r0][l + 128] = acc1;
      A->sc[r0][l + 256] = acc2;
      A->sc[r0][l + 384] = acc3;
      __syncthreads();
      // ---- softmax: wave w owns row w (waves 4-7 idle briefly) ----
      {
        const int wave = tid >> 6, lane = tid & 63;
        if (wave < 4) {
          float v[8];
#pragma unroll
          for (int i = 0; i < 8; ++i) v[i] = A->sc[wave][lane + i * 64];
          float m = v[0];
#pragma unroll
          for (int i = 1; i < 8; ++i) m = fmaxf(m, v[i]);
#pragma unroll
          for (int off = 32; off > 0; off >>= 1) m = fmaxf(m, __shfl_xor(m, off));
          float e[8], s = 0.f;
#pragma unroll
          for (int i = 0; i < 8; ++i) { e[i] = __expf(v[i] - m); s += e[i]; }
#pragma unroll
          for (int off = 32; off > 0; off >>= 1) s += __shfl_xor(s, off);
          const float inv = fast_rcp(s);
#pragma unroll
          for (int i = 0; i < 8; ++i) A->sc[wave][lane + i * 64] = e[i] * inv;
        }
      }
      __syncthreads();
      // ---- weighted sum + concat ----
      const float* attb = att + b * (512 * 128);
      float wa = 0.f;
      for (int k = 0; k < 512; k += 4) {
        float4 p4 = *(const float4*)&A->sc[r0][k];
        wa += p4.x * attb[(k + 0) * 128 + l] + p4.y * attb[(k + 1) * 128 + l]
            + p4.z * attb[(k + 2) * 128 + l] + p4.w * attb[(k + 3) * 128 + l];
      }
      out[row * 256 + 128 + l] = wa;
    }
    return;
  }

  // ================= LSTM scan producer (R15/R17 core; vmcnt(24) PUB schedule) =================
  __builtin_amdgcn_s_setprio(1);  // scan is the critical path
  ScanS* S = (ScanS*)smem;
  const _Float16* xz16 = (const _Float16*)(ws + XZ_OFF);
  const int b_base = blockIdx.x * 4;
  const int w = tid >> 6, lane = tid & 63;
  const int q = lane >> 4, p = lane & 15;
  const int b = p & 3, isel = p >> 2;
  const int u = 16 * w + 4 * isel + q;
  const int bg = b_base + b;

  f16x8 afr[4][4];
#pragma unroll
  for (int i = 0; i < 4; ++i) {
    const int col = (p & 3) * 128 + 16 * w + 4 * i + (p >> 2);
#pragma unroll
    for (int kt = 0; kt < 4; ++kt)
#pragma unroll
      for (int j = 0; j < 8; ++j)
        afr[i][kt][j] = (_Float16)Wrf[(kt * 32 + q * 8 + j) * 512 + col];
  }
  {
    _Float16* hp = &S->hb[0][0];
    for (int i = tid; i < 2 * 576; i += 512) hp[i] = (_Float16)0.f;
  }
  const fx4 zeroC = {0.f, 0.f, 0.f, 0.f};
  float cst = 0.f, hval = 0.f;
  const _Float16* xp = xz16 + (bg * 128 + u) * 4;
  uint2 pf0 = *(const uint2*)(xp);
  uint2 pf1 = *(const uint2*)(xp + 4096);
  uint2 pf2 = *(const uint2*)(xp + 8192);
  __syncthreads();

  const int brow = b * 144;  // stride 144: banks 8b+4q(+2isel) -> 2-way (free)
  for (int t = 0; t < 256; ++t) {
    const _Float16* hrow = &S->hb[t & 1][brow];
    f16x8 bfr[4];
#pragma unroll
    for (int kt = 0; kt < 4; ++kt)
      bfr[kt] = *(const f16x8*)&hrow[kt * 32 + q * 8];
    fx4 acc[4];
#pragma unroll
    for (int i = 0; i < 4; ++i)
      acc[i] = __builtin_amdgcn_mfma_f32_16x16x32_f16(afr[i][0], bfr[0], zeroC, 0, 0, 0);
#pragma unroll
    for (int kt = 1; kt < 4; ++kt)
#pragma unroll
      for (int i = 0; i < 4; ++i)
        acc[i] = __builtin_amdgcn_mfma_f32_16x16x32_f16(afr[i][kt], bfr[kt], acc[i], 0, 0, 0);

    float z[4];
#pragma unroll
    for (int r = 0; r < 4; ++r) {
      float s01 = (isel & 1) ? acc[1][r] : acc[0][r];
      float s23 = (isel & 1) ? acc[3][r] : acc[2][r];
      z[r] = (isel & 2) ? s23 : s01;
    }

    uint2 cur = pf0;
    pf0 = pf1; pf1 = pf2;
    // prefetch issued BEFORE the barrier (R7 position): vmcnt(24) can't stall on it
    const int t3 = (t + 3 < 256) ? t + 3 : 255;
    pf2 = *(const uint2*)(xp + t3 * 4096);

    const _Float16* cf = (const _Float16*)&cur;
    const float zi = z[0] + (float)cf[0];
    const float zf = z[1] + (float)cf[1];
    const float zg = z[2] + (float)cf[2];
    const float zo = z[3] + (float)cf[3];
    cst = fast_sig(zf) * cst + fast_sig(zi) * fast_tanh(zg);
    hval = fast_sig(zo) * fast_tanh(cst);
    S->hb[(t + 1) & 1][brow + u] = (_Float16)hval;
    // agent-scope write-through so consumers on other XCDs see fresh data
    __hip_atomic_store(&xf[(bg * 256 + t) * 128 + u], hval,
                       __ATOMIC_RELAXED, __HIP_MEMORY_SCOPE_AGENT);

    if ((t & 7) == 7) {
      // vmcnt(24): 32 vmem ops (16 stores + 16 loads) issued after xf(t-16)
      // -> waiting to <=24 outstanding proves it drained, waits ~0 cycles.
      PUB_BARRIER();
      if (tid == 0) {
        const int v = t - 15;   // claims rows <= t-16 (= v-1)
        if (v > 0)
          __hip_atomic_store(&prog[blockIdx.x * 64], v,
                             __ATOMIC_RELAXED, __HIP_MEMORY_SCOPE_AGENT);
      }
    } else {
      LDS_BARRIER();  // LDS visibility only; no vmem drain
    }
  }
  // final publication: full drain (covers all stores), then prog = 256
  __syncthreads();
  if (tid == 0)
    __hip_atomic_store(&prog[blockIdx.x * 64], 256,
                       __ATOMIC_RELAXED, __HIP_MEMORY_SCOPE_AGENT);
  out[OUT_H + bg * 128 + u] = hval;
  out[OUT_C + bg * 128 + u] = cst;
}

extern "C" void kernel_launch(void* const* d_in, const int* in_sizes, int n_in,
                              void* d_out, int out_size, void* d_ws, size_t ws_size,
                              hipStream_t stream) {
  const float* inputs   = (const float*)d_in[0];
  const float* attended = (const float*)d_in[1];
  const float* Wk       = (const float*)d_in[2];
  const float* Wr       = (const float*)d_in[3];
  const float* bias     = (const float*)d_in[4];
  const float* W1       = (const float*)d_in[5];
  const float* b1       = (const float*)d_in[6];
  const float* W2       = (const float*)d_in[7];
  const float* b2       = (const float*)d_in[8];
  const float* W3       = (const float*)d_in[9];
  const float* b3       = (const float*)d_in[10];
  float* out = (float*)d_out;
  float* ws = (float*)d_ws;

  hipLaunchKernelGGL(prologue_k, dim3(512), dim3(256), 0, stream,
                     inputs, Wk, bias, attended, W1, b1, ws);
  hipLaunchKernelGGL(fused_scan_attn, dim3(258), dim3(512), 0, stream,
                     Wr, attended, W2, b2, W3, b3, ws, out);
}

// Round 13
// 280.942 us; speedup vs baseline: 1.0345x; 1.0345x over previous
//
#include <hip/hip_runtime.h>
#include <hip/hip_bf16.h>

// Problem: B=8, T_OUT=256, T_IN=512, L=128, D_IN=128, D_ATT=128 (f32 in/out).
// R20 = R17 byte-exact restore (best measured: fused 202.5us, total 281.8us).
// R19's vmcnt(24)/cadence-8 PUB was flat-to-negative (211.5 fused; read-out:
// cadence-4+vmcnt(8) was already at the sweet spot, and/or container clock
// variance). Mechanism elimination table is now complete:
//   publication drain (R15: -4), deeper drain slack (R19: 0/-9), unlock lag
//   (R13: null), worker tail (R14: -47, now ~12us), co-residency (R17: null),
//   MFMA->VALU offload (R16: spill, -77). All exonerated or exhausted.
// Structural floor: 256-step serial scan chain (128 MFMA/block-step ~620cy
// matrix-pipe + exchange/activation/barrier ~= 1400-1800cy/step in fused
// context) + ~12us tail + ~78us fixed harness overhead ~= 282us total.
//
// ws layout (float elements):
#define XF_OFF   0         // f32 x[8*256*128]
#define PROG_OFF 524288    // int prog0 @ +0, prog1 @ +64 (256B apart)
#define XZ_OFF   1048576   // f16[8*256*512] region (2 MB)
#define KEYS_OFF 2097152   // f32 keysT[8][128][512], PRESCALED by CSCALE
// out layout (f32): out(8,256,256) @0, h(8,128) @524288, c(8,128) @525312
#define OUT_H    524288
#define OUT_C    525312

#define LDS_BARRIER() __asm__ __volatile__("s_waitcnt lgkmcnt(0)\n\ts_barrier" ::: "memory")
// Publication barrier: proves xf(t-4) and older drained (>=9 newer ops in
// flight) without waiting on anything recent -> ~0 cost.
#define PUB_BARRIER() __asm__ __volatile__("s_waitcnt vmcnt(8) lgkmcnt(0)\n\ts_barrier" ::: "memory")

#if __has_builtin(__builtin_amdgcn_exp2f)
#define EXP2F __builtin_amdgcn_exp2f
#else
#define EXP2F exp2f
#endif

typedef _Float16 f16x8 __attribute__((ext_vector_type(8)));
typedef float fx4 __attribute__((ext_vector_type(4)));

__device__ __forceinline__ float fast_rcp(float x) { return __builtin_amdgcn_rcpf(x); }
__device__ __forceinline__ float fast_sig(float v) { return fast_rcp(1.f + __expf(-v)); }
__device__ __forceinline__ float fast_tanh(float v) { return 2.f * fast_rcp(1.f + __expf(-2.f * v)) - 1.f; }

// C = -2*log2(e): tanh(v) = 2*rcp(1+exp2(C*v)) - 1
#define CSCALE (-2.8853900817779268f)

// ---------------- Kernel 1: xz prologue (blocks 0-255) + keysT GEMM (256-511) ----------------
__global__ __launch_bounds__(256)
void prologue_k(const float* __restrict__ inp, const float* __restrict__ Wk,
                const float* __restrict__ bias, const float* __restrict__ att,
                const float* __restrict__ W1, const float* __restrict__ b1,
                float* __restrict__ ws) {
  __shared__ float ar[8][128];
  __shared__ float ar2[16][128];
  const int tid = threadIdx.x;

  if (blockIdx.x < 256) {
    // ---- xz = inputs @ Wk + bias, f16 [t][b][u][gate] ----
    _Float16* xz16 = (_Float16*)(ws + XZ_OFF);
    const int row0 = blockIdx.x * 8;
    for (int i = tid; i < 8 * 128; i += 256) ar[i >> 7][i & 127] = inp[row0 * 128 + i];
    __syncthreads();
    float acc[8][2];
    const float bb0 = bias[tid], bb1 = bias[tid + 256];
#pragma unroll
    for (int r = 0; r < 8; ++r) { acc[r][0] = bb0; acc[r][1] = bb1; }
    for (int d = 0; d < 128; d += 4) {
      float w0a = Wk[(d + 0) * 512 + tid], w0b = Wk[(d + 0) * 512 + tid + 256];
      float w1a = Wk[(d + 1) * 512 + tid], w1b = Wk[(d + 1) * 512 + tid + 256];
      float w2a = Wk[(d + 2) * 512 + tid], w2b = Wk[(d + 2) * 512 + tid + 256];
      float w3a = Wk[(d + 3) * 512 + tid], w3b = Wk[(d + 3) * 512 + tid + 256];
#pragma unroll
      for (int r = 0; r < 8; ++r) {
        float4 a4 = *(const float4*)&ar[r][d];
        acc[r][0] += a4.x * w0a + a4.y * w1a + a4.z * w2a + a4.w * w3a;
        acc[r][1] += a4.x * w0b + a4.y * w1b + a4.z * w2b + a4.w * w3b;
      }
    }
    const int u = tid & 127, g0 = tid >> 7;
#pragma unroll
    for (int r = 0; r < 8; ++r) {
      const int row = row0 + r, b = row >> 8, t = row & 255;
      const int base = ((t * 8 + b) * 128 + u) * 4;
      xz16[base + g0]     = (_Float16)acc[r][0];
      xz16[base + g0 + 2] = (_Float16)acc[r][1];
    }
    return;
  }

  // ---- keysT[b][l][k] = CSCALE * ((attended @ W1 + b1))^T : 16 k-rows per block ----
  if (blockIdx.x == 256 && tid < 2) ((int*)(ws + PROG_OFF))[tid * 64] = 0;  // padded prog cells
  const int kb = blockIdx.x - 256;
  const int row0 = kb * 16;              // global row in (b*512 + k)
  const int bq = row0 >> 9, k0 = row0 & 511;
  for (int i = tid; i < 16 * 128; i += 256) ar2[i >> 7][i & 127] = att[row0 * 128 + i];
  __syncthreads();
  const int l = tid & 127, r0 = tid >> 7;  // r0 in 0..1
  float acc[8];
  const float bl = b1[l];
#pragma unroll
  for (int i = 0; i < 8; ++i) acc[i] = bl;
  for (int d = 0; d < 128; d += 4) {
    float w0 = W1[(d + 0) * 128 + l], w1 = W1[(d + 1) * 128 + l];
    float w2 = W1[(d + 2) * 128 + l], w3 = W1[(d + 3) * 128 + l];
#pragma unroll
    for (int i = 0; i < 8; ++i) {
      float4 a4 = *(const float4*)&ar2[r0 * 8 + i][d];
      acc[i] += a4.x * w0 + a4.y * w1 + a4.z * w2 + a4.w * w3;
    }
  }
  float* kT = ws + KEYS_OFF + (bq * 128 + l) * 512 + k0 + r0 * 8;
  float4 lo = {CSCALE * acc[0], CSCALE * acc[1], CSCALE * acc[2], CSCALE * acc[3]};
  float4 hi = {CSCALE * acc[4], CSCALE * acc[5], CSCALE * acc[6], CSCALE * acc[7]};
  *(float4*)kT = lo;
  *(float4*)(kT + 4) = hi;
}

// ---------------- Kernel 2: fused LSTM scan (blocks 0-1) + attention workers ----------------
struct ScanS { _Float16 hb[2][576]; };                       // 2.25 KB (overlay)
struct AttnS {                                               // 45568 B
  float kc[2][8][512];    // keysT strip double-buffer (prescaled)
  float xr[4][128];       // staged x rows
  float qp[4][128];       // q projection (prescaled by CSCALE)
  float sc[4][512];       // scores -> probs
  float w3s[128];         // 2*W3
};

__global__ __launch_bounds__(512)
void fused_scan_attn(const float* __restrict__ Wrf, const float* __restrict__ att,
                     const float* __restrict__ W2c, const float* __restrict__ b2c,
                     const float* __restrict__ W3c, const float* __restrict__ b3c,
                     float* __restrict__ ws, float* __restrict__ out) {
  // 86016B static LDS: 2 blocks would need 168KB > 160KB -> 1 block/CU
  // kernel-wide (scan CUs exclusive).
  __shared__ __align__(16) char smem[86016];
  const int tid = threadIdx.x;
  int* prog = (int*)(ws + PROG_OFF);   // cells at [0] and [64] (256B apart)
  float* xf = ws + XF_OFF;

  if (blockIdx.x >= 2) {
    // ================= attention worker: chunks {w, 511-w}, earlier q0 first =================
    AttnS* A = (AttnS*)smem;
    const int wkr = (int)blockIdx.x - 2;  // 0..255
    int cA = wkr, cB = 511 - wkr;
    if ((cA & 63) > (cB & 63)) { int tmp = cA; cA = cB; cB = tmp; }
    if (tid < 128) A->w3s[tid] = 2.f * W3c[tid];
    // sum(w3) for the tanh->rcp correction (once; W3 is L2-hot)
    float sw3 = 0.f;
    for (int ll = 0; ll < 128; ll += 4) {
      float4 w4 = *(const float4*)&W3c[ll];
      sw3 += w4.x + w4.y + w4.z + w4.w;
    }
    const int l = tid & 127, r0 = tid >> 7;    // one thread per (row, l); r0 in 0..3
    for (int ci = 0; ci < 2; ++ci) {
      const int c = ci ? cB : cA;
      const int b = c >> 6, q0 = (c & 63) * 4;
      if (tid == 0) {
        int pv;
        while ((pv = __hip_atomic_load(&prog[(b >> 2) * 64], __ATOMIC_RELAXED,
                                       __HIP_MEMORY_SCOPE_AGENT)) < q0 + 4) {
          if (q0 + 4 - pv > 32) __builtin_amdgcn_s_sleep(127);   // far: 3.4us backoff
          else                  __builtin_amdgcn_s_sleep(8);     // near: 0.34us
        }
      }
      __syncthreads();   // wake barrier; also orders w3s (ci=0) / prev chunk's sc reads (ci=1)
      const int row = b * 256 + q0 + r0;
      const float xv = __hip_atomic_load(&xf[row * 128 + l], __ATOMIC_RELAXED, __HIP_MEMORY_SCOPE_AGENT);
      A->xr[r0][l] = xv;
      out[row * 256 + l] = xv;
      __syncthreads();
      // ---- qproj (prescaled): qp[r0][l] = CSCALE*(x@W2 + b2) ----
      float qa = b2c[l];
      for (int d = 0; d < 128; d += 4) {
        float4 x4 = *(const float4*)&A->xr[r0][d];
        qa += x4.x * W2c[(d + 0) * 128 + l] + x4.y * W2c[(d + 1) * 128 + l]
            + x4.z * W2c[(d + 2) * 128 + l] + x4.w * W2c[(d + 3) * 128 + l];
      }
      A->qp[r0][l] = CSCALE * qa;      // published by first strip barrier below
      const float base = b3c[0] - sw3;   // b3 + sum_l(-w3): tanh = 2r-1 correction
      // ---- scores: dbuf kc staging, issue-early/write-late, 1 barrier/strip ----
      float acc0 = base, acc1 = base, acc2 = base, acc3 = base;
      const float* keysT = ws + KEYS_OFF + b * (128 * 512);   // prescaled
      float rg[8];
#pragma unroll
      for (int k = 0; k < 8; ++k) rg[k] = keysT[tid + 512 * k];   // strip 0 -> regs
      {
        float* kw = &A->kc[0][0][0];
#pragma unroll
        for (int k = 0; k < 8; ++k) kw[tid + 512 * k] = rg[k];    // strip 0 -> buf 0
      }
      int cur = 0;
      for (int cc = 0; cc < 128; cc += 8) {
        const bool has_next = (cc + 8) < 128;
        if (has_next) {
          const float* nb = keysT + (cc + 8) * 512;
#pragma unroll
          for (int k = 0; k < 8; ++k) rg[k] = nb[tid + 512 * k];  // issue early
        }
        __syncthreads();   // buf[cur] writes (+qp on first strip) visible
        const float* kb = &A->kc[cur][0][0];
#pragma unroll
        for (int lp = 0; lp < 8; ++lp) {
          const float qv = A->qp[r0][cc + lp];  // LDS broadcast
          const float wv = A->w3s[cc + lp];     // LDS broadcast, = 2*w3
          const float* kr = kb + lp * 512;
          acc0 += fast_rcp(1.f + EXP2F(kr[l]       + qv)) * wv;
          acc1 += fast_rcp(1.f + EXP2F(kr[l + 128] + qv)) * wv;
          acc2 += fast_rcp(1.f + EXP2F(kr[l + 256] + qv)) * wv;
          acc3 += fast_rcp(1.f + EXP2F(kr[l + 384] + qv)) * wv;
        }
        if (has_next) {
          float* kw = &A->kc[cur ^ 1][0][0];
#pragma unroll
          for (int k = 0; k < 8; ++k) kw[tid + 512 * k] = rg[k];  // write late
        }
        cur ^= 1;
      }
      A->sc[r0][l]       = acc0;
      A->sc[r0][l + 128] = acc1;
      A->sc[r0][l + 256] = acc2;
      A->sc[r0][l + 384] = acc3;
      __syncthreads();
      // ---- softmax: wave w owns row w (waves 4-7 idle briefly) ----
      {
        const int wave = tid >> 6, lane = tid & 63;
        if (wave < 4) {
          float v[8];
#pragma unroll
          for (int i = 0; i < 8; ++i) v[i] = A->sc[wave][lane + i * 64];
          float m = v[0];
#pragma unroll
          for (int i = 1; i < 8; ++i) m = fmaxf(m, v[i]);
#pragma unroll
          for (int off = 32; off > 0; off >>= 1) m = fmaxf(m, __shfl_xor(m, off));
          float e[8], s = 0.f;
#pragma unroll
          for (int i = 0; i < 8; ++i) { e[i] = __expf(v[i] - m); s += e[i]; }
#pragma unroll
          for (int off = 32; off > 0; off >>= 1) s += __shfl_xor(s, off);
          const float inv = fast_rcp(s);
#pragma unroll
          for (int i = 0; i < 8; ++i) A->sc[wave][lane + i * 64] = e[i] * inv;
        }
      }
      __syncthreads();
      // ---- weighted sum + concat ----
      const float* attb = att + b * (512 * 128);
      float wa = 0.f;
      for (int k = 0; k < 512; k += 4) {
        float4 p4 = *(const float4*)&A->sc[r0][k];
        wa += p4.x * attb[(k + 0) * 128 + l] + p4.y * attb[(k + 1) * 128 + l]
            + p4.z * attb[(k + 2) * 128 + l] + p4.w * attb[(k + 3) * 128 + l];
      }
      out[row * 256 + 128 + l] = wa;
    }
    return;
  }

  // ================= LSTM scan producer (R15-exact core) =================
  __builtin_amdgcn_s_setprio(1);  // scan is the critical path
  ScanS* S = (ScanS*)smem;
  const _Float16* xz16 = (const _Float16*)(ws + XZ_OFF);
  const int b_base = blockIdx.x * 4;
  const int w = tid >> 6, lane = tid & 63;
  const int q = lane >> 4, p = lane & 15;
  const int b = p & 3, isel = p >> 2;
  const int u = 16 * w + 4 * isel + q;
  const int bg = b_base + b;

  f16x8 afr[4][4];
#pragma unroll
  for (int i = 0; i < 4; ++i) {
    const int col = (p & 3) * 128 + 16 * w + 4 * i + (p >> 2);
#pragma unroll
    for (int kt = 0; kt < 4; ++kt)
#pragma unroll
      for (int j = 0; j < 8; ++j)
        afr[i][kt][j] = (_Float16)Wrf[(kt * 32 + q * 8 + j) * 512 + col];
  }
  {
    _Float16* hp = &S->hb[0][0];
    for (int i = tid; i < 2 * 576; i += 512) hp[i] = (_Float16)0.f;
  }
  const fx4 zeroC = {0.f, 0.f, 0.f, 0.f};
  float cst = 0.f, hval = 0.f;
  const _Float16* xp = xz16 + (bg * 128 + u) * 4;
  uint2 pf0 = *(const uint2*)(xp);
  uint2 pf1 = *(const uint2*)(xp + 4096);
  uint2 pf2 = *(const uint2*)(xp + 8192);
  __syncthreads();

  const int brow = b * 144;  // stride 144: banks 8b+4q(+2isel) -> 2-way (free)
  for (int t = 0; t < 256; ++t) {
    const _Float16* hrow = &S->hb[t & 1][brow];
    f16x8 bfr[4];
#pragma unroll
    for (int kt = 0; kt < 4; ++kt)
      bfr[kt] = *(const f16x8*)&hrow[kt * 32 + q * 8];
    fx4 acc[4];
#pragma unroll
    for (int i = 0; i < 4; ++i)
      acc[i] = __builtin_amdgcn_mfma_f32_16x16x32_f16(afr[i][0], bfr[0], zeroC, 0, 0, 0);
#pragma unroll
    for (int kt = 1; kt < 4; ++kt)
#pragma unroll
      for (int i = 0; i < 4; ++i)
        acc[i] = __builtin_amdgcn_mfma_f32_16x16x32_f16(afr[i][kt], bfr[kt], acc[i], 0, 0, 0);

    float z[4];
#pragma unroll
    for (int r = 0; r < 4; ++r) {
      float s01 = (isel & 1) ? acc[1][r] : acc[0][r];
      float s23 = (isel & 1) ? acc[3][r] : acc[2][r];
      z[r] = (isel & 2) ? s23 : s01;
    }

    uint2 cur = pf0;
    pf0 = pf1; pf1 = pf2;

    const _Float16* cf = (const _Float16*)&cur;
    const float zi = z[0] + (float)cf[0];
    const float zf = z[1] + (float)cf[1];
    const float zg = z[2] + (float)cf[2];
    const float zo = z[3] + (float)cf[3];
    cst = fast_sig(zf) * cst + fast_sig(zi) * fast_tanh(zg);
    hval = fast_sig(zo) * fast_tanh(cst);
    S->hb[(t + 1) & 1][brow + u] = (_Float16)hval;
    // agent-scope write-through so consumers on other XCDs see fresh data
    __hip_atomic_store(&xf[(bg * 256 + t) * 128 + u], hval,
                       __ATOMIC_RELAXED, __HIP_MEMORY_SCOPE_AGENT);

    if ((t & 3) == 3) {
      // vmcnt(8): >=9 vmem ops issued after xf(t-4) -> proves it drained,
      // waits ~0 cycles. Claim rows 0..t-4 (prog = t-3).
      PUB_BARRIER();
      if (tid == 0)
        __hip_atomic_store(&prog[blockIdx.x * 64], t - 3,
                           __ATOMIC_RELAXED, __HIP_MEMORY_SCOPE_AGENT);
    } else {
      LDS_BARRIER();  // LDS visibility only; no vmem drain
    }
    // issue prefetch AFTER the barrier so publication wait doesn't cover it
    const int t3 = (t + 3 < 256) ? t + 3 : 255;
    pf2 = *(const uint2*)(xp + t3 * 4096);
  }
  // final publication: full drain (covers all stores), then prog = 256
  __syncthreads();
  if (tid == 0)
    __hip_atomic_store(&prog[blockIdx.x * 64], 256,
                       __ATOMIC_RELAXED, __HIP_MEMORY_SCOPE_AGENT);
  out[OUT_H + bg * 128 + u] = hval;
  out[OUT_C + bg * 128 + u] = cst;
}

extern "C" void kernel_launch(void* const* d_in, const int* in_sizes, int n_in,
                              void* d_out, int out_size, void* d_ws, size_t ws_size,
                              hipStream_t stream) {
  const float* inputs   = (const float*)d_in[0];
  const float* attended = (const float*)d_in[1];
  const float* Wk       = (const float*)d_in[2];
  const float* Wr       = (const float*)d_in[3];
  const float* bias     = (const float*)d_in[4];
  const float* W1       = (const float*)d_in[5];
  const float* b1       = (const float*)d_in[6];
  const float* W2       = (const float*)d_in[7];
  const float* b2       = (const float*)d_in[8];
  const float* W3       = (const float*)d_in[9];
  const float* b3       = (const float*)d_in[10];
  float* out = (float*)d_out;
  float* ws = (float*)d_ws;

  hipLaunchKernelGGL(prologue_k, dim3(512), dim3(256), 0, stream,
                     inputs, Wk, bias, attended, W1, b1, ws);
  hipLaunchKernelGGL(fused_scan_attn, dim3(258), dim3(512), 0, stream,
                     Wr, attended, W2, b2, W3, b3, ws, out);
}